// Round 2
// baseline (22043.768 us; speedup 1.0000x reference)
//
#include <hip/hip_runtime.h>
#include <hip/hip_bf16.h>
#include <math.h>

typedef __hip_bfloat16 bf16;

static constexpr int B_ = 8, C_ = 128, H_ = 128, W_ = 128;
static constexpr int N_ = H_ * W_;          // 16384
static constexpr int NWIN = 648;            // B * 9 * 9

__device__ __forceinline__ float b2f(bf16 v) { return __bfloat162float(v); }
__device__ __forceinline__ bf16 f2b(float v) { return __float2bfloat16(v); }
__device__ __forceinline__ float gelu_f(float x) {
    return 0.5f * x * (1.0f + erff(x * 0.70710678118654752f));
}

// ---------------- K1: 2x2 avg pool (fp32) ----------------
__global__ __launch_bounds__(256) void k_pool(const float* __restrict__ x, float* __restrict__ low) {
    int idx = blockIdx.x * 256 + threadIdx.x;       // 4,194,304
    int j = idx & 63, i = (idx >> 6) & 63, bc = idx >> 12;
    const float* p = x + (size_t)bc * N_ + (i * 2) * W_ + j * 2;
    low[idx] = (p[0] + p[1] + p[W_] + p[W_ + 1]) * 0.25f;
}

// ---------------- K2: hf = x - bilinear_up(low)  (bf16 out) ----------------
__global__ __launch_bounds__(256) void k_hf(const float* __restrict__ x, const float* __restrict__ low,
                                            bf16* __restrict__ hf) {
    int idx = blockIdx.x * 256 + threadIdx.x;       // 16,777,216
    int w = idx & 127, h = (idx >> 7) & 127, bc = idx >> 14;
    int jh = h >> 1, jw = w >> 1;
    int h0, h1; float wh0, wh1;
    if (h & 1) { h0 = jh; h1 = jh + 1 > 63 ? 63 : jh + 1; wh0 = 0.75f; wh1 = 0.25f; }
    else       { h0 = jh - 1 < 0 ? 0 : jh - 1; h1 = jh;   wh0 = 0.25f; wh1 = 0.75f; }
    int w0, w1; float ww0, ww1;
    if (w & 1) { w0 = jw; w1 = jw + 1 > 63 ? 63 : jw + 1; ww0 = 0.75f; ww1 = 0.25f; }
    else       { w0 = jw - 1 < 0 ? 0 : jw - 1; w1 = jw;   ww0 = 0.25f; ww1 = 0.75f; }
    const float* lp = low + (size_t)bc * 4096;
    float up = wh0 * (ww0 * lp[h0 * 64 + w0] + ww1 * lp[h0 * 64 + w1])
             + wh1 * (ww0 * lp[h1 * 64 + w0] + ww1 * lp[h1 * 64 + w1]);
    hf[idx] = f2b(x[idx] - up);
}

// ---------------- K3: sgate (fp32 out) ----------------
__global__ __launch_bounds__(256) void k_sgate(const bf16* __restrict__ hf, const float* __restrict__ gw,
                                               const float* __restrict__ gb, float* __restrict__ sg) {
    int idx = blockIdx.x * 256 + threadIdx.x;       // 131072
    int n = idx & (N_ - 1); int b = idx >> 14;
    const bf16* p = hf + (size_t)b * C_ * N_ + n;
    float s = 0.f;
    for (int c = 0; c < C_; ++c) s += gw[c] * fabsf(b2f(p[(size_t)c * N_]));
    s += gb[0];
    sg[idx] = 1.0f / (1.0f + expf(-s));
}

// ---------------- K4: g = gelu(dwconv3x3 dil2) (bf16) ----------------
__global__ __launch_bounds__(256) void k_dw3(const bf16* __restrict__ hf, const float* __restrict__ wdw,
                                             bf16* __restrict__ g) {
    int idx = blockIdx.x * 256 + threadIdx.x;
    int w = idx & 127, h = (idx >> 7) & 127, bc = idx >> 14, c = bc & 127;
    const bf16* p = hf + (size_t)bc * N_;
    const float* kw = wdw + c * 9;
    float s = 0.f;
    #pragma unroll
    for (int ky = 0; ky < 3; ++ky) {
        int hh = h + (ky - 1) * 2;
        if ((unsigned)hh >= 128u) continue;
        #pragma unroll
        for (int kx = 0; kx < 3; ++kx) {
            int ww = w + (kx - 1) * 2;
            if ((unsigned)ww >= 128u) continue;
            s += kw[ky * 3 + kx] * b2f(p[hh * W_ + ww]);
        }
    }
    g[idx] = f2b(gelu_f(s));
}

// ---------------- K5: pw GEMM + LTH epilogue -> x1 (bf16) ----------------
__global__ __launch_bounds__(256) void k_pw(const bf16* __restrict__ g, const float* __restrict__ pww,
                                            const float* __restrict__ pwb, const float* __restrict__ x,
                                            const float* __restrict__ scale, const float* __restrict__ sg,
                                            bf16* __restrict__ x1) {
    __shared__ __align__(16) float a_lds[128][64];
    __shared__ __align__(16) float w_lds[16][128];
    int tid = threadIdx.x;
    int gtok = blockIdx.x * 64; int b = gtok >> 14; int nb = gtok & (N_ - 1);
    const bf16* A = g + (size_t)b * C_ * N_ + nb;
    for (int e = tid; e < 8192; e += 256) { int c = e >> 6, i = e & 63; a_lds[c][i] = b2f(A[(size_t)c * N_ + i]); }
    int tn = tid & 15, to = tid >> 4;
    float acc[4][8] = {};
    for (int c0 = 0; c0 < 128; c0 += 16) {
        __syncthreads();
        for (int e = tid; e < 2048; e += 256) { int cc = e & 15, o = e >> 4; w_lds[cc][o] = pww[o * 128 + c0 + cc]; }
        __syncthreads();
        for (int cc = 0; cc < 16; ++cc) {
            float4 a4 = *(const float4*)&a_lds[c0 + cc][tn * 4];
            const float4* wr4 = (const float4*)&w_lds[cc][to * 8];
            float4 wa = wr4[0], wb = wr4[1];
            float wv[8] = {wa.x, wa.y, wa.z, wa.w, wb.x, wb.y, wb.z, wb.w};
            #pragma unroll
            for (int oj = 0; oj < 8; ++oj) {
                float wvv = wv[oj];
                acc[0][oj] += a4.x * wvv; acc[1][oj] += a4.y * wvv;
                acc[2][oj] += a4.z * wvv; acc[3][oj] += a4.w * wvv;
            }
        }
    }
    #pragma unroll
    for (int rr = 0; rr < 4; ++rr) {
        int n = nb + tn * 4 + rr;
        float sgv = sg[(b << 14) + n];
        #pragma unroll
        for (int oj = 0; oj < 8; ++oj) {
            int o = to * 8 + oj;
            size_t oaddr = (size_t)(b * C_ + o) * N_ + n;
            x1[oaddr] = f2b(x[oaddr] + scale[o] * (acc[rr][oj] + pwb[o]) * sgv);
        }
    }
}

// ---------------- K6: fused LN1 + qkv GEMM -> q,k,v (bf16) ----------------
__global__ __launch_bounds__(256) void k_qkv(const bf16* __restrict__ x1, const float* __restrict__ lng,
                                             const float* __restrict__ lnb, const float* __restrict__ qkvw,
                                             bf16* __restrict__ q, bf16* __restrict__ k, bf16* __restrict__ v) {
    __shared__ __align__(16) float y_lds[128][64];
    __shared__ __align__(16) float w_lds[16][128];
    __shared__ float red2[8][64];
    __shared__ float mu_l[64], rs_l[64];
    int tid = threadIdx.x;
    int win = blockIdx.x >> 2; int tokbase = (blockIdx.x & 3) * 64;
    int b = win / 81; int r0 = win % 81; int top = (r0 / 9) * 14, left = (r0 % 9) * 14;
    for (int e = tid; e < 8192; e += 256) {
        int c = e >> 6, i = e & 63; int tok = tokbase + i; int p = tok >> 4, qq = tok & 15;
        y_lds[c][i] = b2f(x1[(size_t)(b * C_ + c) * N_ + (top + p) * W_ + (left + qq)]);
    }
    __syncthreads();
    { // LN stats: 4 partials per token
        int i = tid & 63, r = tid >> 6;
        float s = 0.f, ss = 0.f;
        for (int cc = r * 32; cc < r * 32 + 32; ++cc) { float vv = y_lds[cc][i]; s += vv; ss += vv * vv; }
        red2[r][i] = s; red2[4 + r][i] = ss;
    }
    __syncthreads();
    if (tid < 64) {
        float s = red2[0][tid] + red2[1][tid] + red2[2][tid] + red2[3][tid];
        float ss = red2[4][tid] + red2[5][tid] + red2[6][tid] + red2[7][tid];
        float mu = s * (1.f / 128.f); float var = ss * (1.f / 128.f) - mu * mu;
        mu_l[tid] = mu; rs_l[tid] = rsqrtf(var + 1e-6f);
    }
    __syncthreads();
    for (int e = tid; e < 8192; e += 256) {
        int c = e >> 6, i = e & 63;
        y_lds[c][i] = (y_lds[c][i] - mu_l[i]) * rs_l[i] * lng[c] + lnb[c];
    }
    int tn = tid & 15, to = tid >> 4;
    for (int pass = 0; pass < 3; ++pass) {
        float acc[4][8] = {};
        for (int c0 = 0; c0 < 128; c0 += 16) {
            __syncthreads();
            for (int e = tid; e < 2048; e += 256) { int cc = e >> 7, o = e & 127; w_lds[cc][o] = qkvw[(c0 + cc) * 384 + pass * 128 + o]; }
            __syncthreads();
            for (int cc = 0; cc < 16; ++cc) {
                float4 a4 = *(const float4*)&y_lds[c0 + cc][tn * 4];
                const float4* wr4 = (const float4*)&w_lds[cc][to * 8];
                float4 wa = wr4[0], wb = wr4[1];
                float wv[8] = {wa.x, wa.y, wa.z, wa.w, wb.x, wb.y, wb.z, wb.w};
                #pragma unroll
                for (int oj = 0; oj < 8; ++oj) {
                    float wvv = wv[oj];
                    acc[0][oj] += a4.x * wvv; acc[1][oj] += a4.y * wvv;
                    acc[2][oj] += a4.z * wvv; acc[3][oj] += a4.w * wvv;
                }
            }
        }
        bf16* outp = (pass == 0) ? q : (pass == 1) ? k : v;
        #pragma unroll
        for (int rr = 0; rr < 4; ++rr) {
            int tok = tokbase + tn * 4 + rr;
            #pragma unroll
            for (int oj = 0; oj < 8; ++oj) {
                outp[(size_t)win * 32768 + (to * 8 + oj) * 256 + tok] = f2b(acc[rr][oj]);
            }
        }
        __syncthreads();
    }
}

// ---------------- K7: fused LN1 + gate-z + attention + PE + proj + residual -> t2 (bf16) ----------------
__global__ __launch_bounds__(256) void k_attn(const bf16* __restrict__ x1, const bf16* __restrict__ qb,
                                              const bf16* __restrict__ kb, const bf16* __restrict__ vb,
                                              const float* __restrict__ lng, const float* __restrict__ lnb,
                                              const float* __restrict__ gatew, const float* __restrict__ gateb,
                                              const float* __restrict__ pew, const float* __restrict__ peb,
                                              const float* __restrict__ projw, bf16* __restrict__ t2) {
    __shared__ __align__(16) float y_lds[128][64];    // LN out -> later gated attn out (proj A)
    __shared__ __align__(16) float q_lds[128][64];
    __shared__ __align__(16) float kv_lds[4352];      // k/v chunks + weight staging
    __shared__ __align__(16) bf16 xt_lds[128][64];    // raw crop (residual)
    __shared__ bf16 probs[64][258];
    __shared__ float red[64][17];
    __shared__ float red2[8][64];
    __shared__ float mu_l[64], rs_l[64];
    int tid = threadIdx.x;
    int win = blockIdx.x >> 2; int tokbase = (blockIdx.x & 3) * 64;
    int b = win / 81; int r0 = win % 81; int top = (r0 / 9) * 14, left = (r0 % 9) * 14;
    const bf16* qg = qb + (size_t)win * 32768;
    const bf16* kg = kb + (size_t)win * 32768;
    const bf16* vg = vb + (size_t)win * 32768;
    for (int e = tid; e < 8192; e += 256) {
        int c = e >> 6, i = e & 63; int tok = tokbase + i; int p = tok >> 4, qq = tok & 15;
        xt_lds[c][i] = x1[(size_t)(b * C_ + c) * N_ + (top + p) * W_ + (left + qq)];
        q_lds[c][i] = b2f(qg[c * 256 + tokbase + i]);
    }
    __syncthreads();
    { // LN stats
        int i = tid & 63, r = tid >> 6;
        float s = 0.f, ss = 0.f;
        for (int cc = r * 32; cc < r * 32 + 32; ++cc) { float vv = b2f(xt_lds[cc][i]); s += vv; ss += vv * vv; }
        red2[r][i] = s; red2[4 + r][i] = ss;
    }
    __syncthreads();
    if (tid < 64) {
        float s = red2[0][tid] + red2[1][tid] + red2[2][tid] + red2[3][tid];
        float ss = red2[4][tid] + red2[5][tid] + red2[6][tid] + red2[7][tid];
        float mu = s * (1.f / 128.f); float var = ss * (1.f / 128.f) - mu * mu;
        mu_l[tid] = mu; rs_l[tid] = rsqrtf(var + 1e-6f);
    }
    __syncthreads();
    for (int e = tid; e < 8192; e += 256) {
        int c = e >> 6, i = e & 63;
        y_lds[c][i] = (b2f(xt_lds[c][i]) - mu_l[i]) * rs_l[i] * lng[c] + lnb[c];
    }
    int tn = tid & 15, to = tid >> 4;
    // ---- z = gelu(y @ gate_w + gate_b) ----
    float zv[4][8] = {};
    for (int c0 = 0; c0 < 128; c0 += 16) {
        __syncthreads();
        for (int e = tid; e < 2048; e += 256) { int cc = e >> 7, o = e & 127; kv_lds[cc * 128 + o] = gatew[(c0 + cc) * 128 + o]; }
        __syncthreads();
        for (int cc = 0; cc < 16; ++cc) {
            float4 a4 = *(const float4*)&y_lds[c0 + cc][tn * 4];
            const float4* wr4 = (const float4*)&kv_lds[cc * 128 + to * 8];
            float4 wa = wr4[0], wb = wr4[1];
            float wv[8] = {wa.x, wa.y, wa.z, wa.w, wb.x, wb.y, wb.z, wb.w};
            #pragma unroll
            for (int oj = 0; oj < 8; ++oj) {
                float wvv = wv[oj];
                zv[0][oj] += a4.x * wvv; zv[1][oj] += a4.y * wvv;
                zv[2][oj] += a4.z * wvv; zv[3][oj] += a4.w * wvv;
            }
        }
    }
    #pragma unroll
    for (int rr = 0; rr < 4; ++rr)
        #pragma unroll
        for (int oj = 0; oj < 8; ++oj) zv[rr][oj] = gelu_f(zv[rr][oj] + gateb[to * 8 + oj]);
    // ---- scores = q @ k^T ----
    float s[4][16] = {};
    for (int c0 = 0; c0 < 128; c0 += 16) {
        __syncthreads();
        for (int e = tid; e < 4096; e += 256) { int cc = e >> 8, j = e & 255; kv_lds[cc * 256 + j] = b2f(kg[(c0 + cc) * 256 + j]); }
        __syncthreads();
        for (int cc = 0; cc < 16; ++cc) {
            float4 a4 = *(const float4*)&q_lds[c0 + cc][tn * 4];
            const float4* kr4 = (const float4*)&kv_lds[cc * 256 + to * 16];
            float4 w0 = kr4[0], w1 = kr4[1], w2 = kr4[2], w3 = kr4[3];
            float kvv[16] = {w0.x, w0.y, w0.z, w0.w, w1.x, w1.y, w1.z, w1.w,
                             w2.x, w2.y, w2.z, w2.w, w3.x, w3.y, w3.z, w3.w};
            #pragma unroll
            for (int jj = 0; jj < 16; ++jj) {
                float kv = kvv[jj];
                s[0][jj] += a4.x * kv; s[1][jj] += a4.y * kv;
                s[2][jj] += a4.z * kv; s[3][jj] += a4.w * kv;
            }
        }
    }
    const float sm_scale = 0.08838834764831845f;   // 128^-0.5
    float rowsum[4];
    #pragma unroll
    for (int rr = 0; rr < 4; ++rr) {
        float m = s[rr][0];
        #pragma unroll
        for (int jj = 1; jj < 16; ++jj) m = fmaxf(m, s[rr][jj]);
        red[tn * 4 + rr][to] = m;
    }
    __syncthreads();
    float rowm[4];
    #pragma unroll
    for (int rr = 0; rr < 4; ++rr) {
        float m = -1e30f;
        for (int u = 0; u < 16; ++u) m = fmaxf(m, red[tn * 4 + rr][u]);
        rowm[rr] = m;
    }
    __syncthreads();
    #pragma unroll
    for (int rr = 0; rr < 4; ++rr) {
        float ls = 0.f;
        #pragma unroll
        for (int jj = 0; jj < 16; ++jj) {
            float p = __expf((s[rr][jj] - rowm[rr]) * sm_scale);
            probs[tn * 4 + rr][to * 16 + jj] = f2b(p);
            ls += p;
        }
        red[tn * 4 + rr][to] = ls;
    }
    __syncthreads();
    #pragma unroll
    for (int rr = 0; rr < 4; ++rr) {
        float ssum = 0.f;
        for (int u = 0; u < 16; ++u) ssum += red[tn * 4 + rr][u];
        rowsum[rr] = ssum;
    }
    // ---- PV ----
    float oacc[4][8] = {};
    for (int k0 = 0; k0 < 256; k0 += 32) {
        __syncthreads();
        for (int e = tid; e < 4096; e += 256) { int c = e >> 5, kk = e & 31; kv_lds[kk * 132 + c] = b2f(vg[c * 256 + k0 + kk]); }
        __syncthreads();
        for (int kk = 0; kk < 32; ++kk) {
            float p0 = b2f(probs[tn * 4 + 0][k0 + kk]);
            float p1 = b2f(probs[tn * 4 + 1][k0 + kk]);
            float p2 = b2f(probs[tn * 4 + 2][k0 + kk]);
            float p3 = b2f(probs[tn * 4 + 3][k0 + kk]);
            const float4* vr4 = (const float4*)&kv_lds[kk * 132 + to * 8];
            float4 va = vr4[0], vb4 = vr4[1];
            float vv[8] = {va.x, va.y, va.z, va.w, vb4.x, vb4.y, vb4.z, vb4.w};
            #pragma unroll
            for (int cc = 0; cc < 8; ++cc) {
                float vvv = vv[cc];
                oacc[0][cc] += p0 * vvv; oacc[1][cc] += p1 * vvv;
                oacc[2][cc] += p2 * vvv; oacc[3][cc] += p3 * vvv;
            }
        }
    }
    // ---- PE + gate; write gated result as proj A-matrix into y_lds ----
    #pragma unroll
    for (int rr = 0; rr < 4; ++rr) {
        int tok = tokbase + tn * 4 + rr;
        int pp = tok >> 4, qq = tok & 15;
        float inv = 1.0f / rowsum[rr];
        #pragma unroll
        for (int cc = 0; cc < 8; ++cc) {
            int c = to * 8 + cc;
            float pv = peb[c];
            #pragma unroll
            for (int ky = 0; ky < 3; ++ky) {
                int py = pp + ky - 1;
                if ((unsigned)py >= 16u) continue;
                #pragma unroll
                for (int kx = 0; kx < 3; ++kx) {
                    int qx = qq + kx - 1;
                    if ((unsigned)qx >= 16u) continue;
                    pv += pew[c * 9 + ky * 3 + kx] * b2f(qg[c * 256 + py * 16 + qx]);
                }
            }
            y_lds[c][tn * 4 + rr] = (oacc[rr][cc] * inv + pv) * zv[rr][cc];
        }
    }
    // ---- proj GEMM + crop residual -> t2 ----
    float pacc[4][8] = {};
    for (int c0 = 0; c0 < 128; c0 += 16) {
        __syncthreads();
        for (int e = tid; e < 2048; e += 256) { int cc = e >> 7, o = e & 127; kv_lds[cc * 128 + o] = projw[(c0 + cc) * 128 + o]; }
        __syncthreads();
        for (int cc = 0; cc < 16; ++cc) {
            float4 a4 = *(const float4*)&y_lds[c0 + cc][tn * 4];
            const float4* wr4 = (const float4*)&kv_lds[cc * 128 + to * 8];
            float4 wa = wr4[0], wb = wr4[1];
            float wv[8] = {wa.x, wa.y, wa.z, wa.w, wb.x, wb.y, wb.z, wb.w};
            #pragma unroll
            for (int oj = 0; oj < 8; ++oj) {
                float wvv = wv[oj];
                pacc[0][oj] += a4.x * wvv; pacc[1][oj] += a4.y * wvv;
                pacc[2][oj] += a4.z * wvv; pacc[3][oj] += a4.w * wvv;
            }
        }
    }
    #pragma unroll
    for (int rr = 0; rr < 4; ++rr) {
        int tok = tokbase + tn * 4 + rr;
        #pragma unroll
        for (int oj = 0; oj < 8; ++oj) {
            int o = to * 8 + oj;
            t2[(size_t)win * 32768 + o * 256 + tok] = f2b(pacc[rr][oj] + b2f(xt_lds[o][tn * 4 + rr]));
        }
    }
}

// ---------------- K8: overlap-fold with divisor -> x2 (bf16) ----------------
__global__ __launch_bounds__(256) void k_fold(const bf16* __restrict__ t2, bf16* __restrict__ x2) {
    int idx = blockIdx.x * 256 + threadIdx.x;      // 16,777,216
    int w = idx & 127, h = (idx >> 7) & 127, c = (idx >> 14) & 127, b = idx >> 21;
    int imin = (h < 16) ? 0 : (h - 2) / 14; int imax = h / 14; if (imax > 8) imax = 8;
    int jmin = (w < 16) ? 0 : (w - 2) / 14; int jmax = w / 14; if (jmax > 8) jmax = 8;
    float sum = 0.f;
    for (int i = imin; i <= imax; ++i)
        for (int j = jmin; j <= jmax; ++j) {
            int win = (b * 9 + i) * 9 + j;
            sum += b2f(t2[(size_t)win * 32768 + c * 256 + (h - i * 14) * 16 + (w - j * 14)]);
        }
    int cnt = (imax - imin + 1) * (jmax - jmin + 1);
    x2[idx] = f2b(sum / (float)cnt);
}

// ---------------- K9: LN2 -> xn (bf16) ----------------
__global__ __launch_bounds__(256) void k_ln2(const bf16* __restrict__ x2, const float* __restrict__ gam,
                                             const float* __restrict__ bet, bf16* __restrict__ xn) {
    int idx = blockIdx.x * 256 + threadIdx.x;      // 131072
    int n = idx & (N_ - 1); int b = idx >> 14;
    const bf16* p = x2 + (size_t)b * C_ * N_ + n;
    float s = 0.f, ss = 0.f;
    for (int c = 0; c < C_; ++c) { float v = b2f(p[(size_t)c * N_]); s += v; ss += v * v; }
    float mu = s * (1.f / 128.f);
    float var = ss * (1.f / 128.f) - mu * mu;
    float rs = rsqrtf(var + 1e-6f);
    bf16* o = xn + (size_t)b * C_ * N_ + n;
    for (int c = 0; c < C_; ++c) o[(size_t)c * N_] = f2b((b2f(p[(size_t)c * N_]) - mu) * rs * gam[c] + bet[c]);
}

// ---------------- K10: fc1 GEMM + gelu -> h1 (bf16) ----------------
__global__ __launch_bounds__(256) void k_fc1(const bf16* __restrict__ xn, const float* __restrict__ w1,
                                             const float* __restrict__ b1, bf16* __restrict__ h1) {
    __shared__ __align__(16) float a_lds[128][64];
    __shared__ __align__(16) float w_lds[16][256];
    int tid = threadIdx.x;
    int gtok = blockIdx.x * 64; int b = gtok >> 14; int nb = gtok & (N_ - 1);
    const bf16* A = xn + (size_t)b * C_ * N_ + nb;
    for (int e = tid; e < 8192; e += 256) { int c = e >> 6, i = e & 63; a_lds[c][i] = b2f(A[(size_t)c * N_ + i]); }
    int tn = tid & 15, to = tid >> 4;
    float acc[4][16] = {};
    for (int c0 = 0; c0 < 128; c0 += 16) {
        __syncthreads();
        for (int e = tid; e < 4096; e += 256) { int cc = e >> 8, o = e & 255; w_lds[cc][o] = w1[(c0 + cc) * 256 + o]; }
        __syncthreads();
        for (int cc = 0; cc < 16; ++cc) {
            float4 a4 = *(const float4*)&a_lds[c0 + cc][tn * 4];
            const float4* wr4 = (const float4*)&w_lds[cc][to * 16];
            float4 w0 = wr4[0], w1v = wr4[1], w2 = wr4[2], w3 = wr4[3];
            float wv[16] = {w0.x, w0.y, w0.z, w0.w, w1v.x, w1v.y, w1v.z, w1v.w,
                            w2.x, w2.y, w2.z, w2.w, w3.x, w3.y, w3.z, w3.w};
            #pragma unroll
            for (int oj = 0; oj < 16; ++oj) {
                float wvv = wv[oj];
                acc[0][oj] += a4.x * wvv; acc[1][oj] += a4.y * wvv;
                acc[2][oj] += a4.z * wvv; acc[3][oj] += a4.w * wvv;
            }
        }
    }
    #pragma unroll
    for (int rr = 0; rr < 4; ++rr) {
        int n = nb + tn * 4 + rr;
        #pragma unroll
        for (int oj = 0; oj < 16; ++oj) {
            int o = to * 16 + oj;
            h1[(size_t)(b * 256 + o) * N_ + n] = f2b(gelu_f(acc[rr][oj] + b1[o]));
        }
    }
}

// ---------------- K11: h2 = h1 + dwconv5x5(h1) + dw_b (bf16) ----------------
__global__ __launch_bounds__(256) void k_dw5(const bf16* __restrict__ h1, const float* __restrict__ wdw,
                                             const float* __restrict__ bdw, bf16* __restrict__ h2) {
    int idx = blockIdx.x * 256 + threadIdx.x;      // 33,554,432
    int w = idx & 127, h = (idx >> 7) & 127, ch = (idx >> 14) & 255, b = idx >> 22;
    const bf16* p = h1 + (size_t)(b * 256 + ch) * N_;
    const float* kw = wdw + ch * 25;
    float s = 0.f;
    #pragma unroll
    for (int ky = 0; ky < 5; ++ky) {
        int hh = h + ky - 2;
        if ((unsigned)hh >= 128u) continue;
        #pragma unroll
        for (int kx = 0; kx < 5; ++kx) {
            int ww = w + kx - 2;
            if ((unsigned)ww >= 128u) continue;
            s += kw[ky * 5 + kx] * b2f(p[hh * W_ + ww]);
        }
    }
    h2[idx] = f2b(b2f(p[h * W_ + w]) + s + bdw[ch]);
}

// ---------------- K12: fc2 GEMM + bias + residual -> d_out (fp32) ----------------
__global__ __launch_bounds__(256) void k_fc2(const bf16* __restrict__ h2, const float* __restrict__ w2,
                                             const float* __restrict__ b2, const bf16* __restrict__ x2,
                                             float* __restrict__ out) {
    __shared__ __align__(16) float a_lds[256][64];
    __shared__ __align__(16) float w_lds[16][128];
    int tid = threadIdx.x;
    int gtok = blockIdx.x * 64; int b = gtok >> 14; int nb = gtok & (N_ - 1);
    const bf16* A = h2 + (size_t)b * 256 * N_ + nb;
    for (int e = tid; e < 16384; e += 256) { int c = e >> 6, i = e & 63; a_lds[c][i] = b2f(A[(size_t)c * N_ + i]); }
    int tn = tid & 15, to = tid >> 4;
    float acc[4][8] = {};
    for (int c0 = 0; c0 < 256; c0 += 16) {
        __syncthreads();
        for (int e = tid; e < 2048; e += 256) { int cc = e >> 7, o = e & 127; w_lds[cc][o] = w2[(c0 + cc) * 128 + o]; }
        __syncthreads();
        for (int cc = 0; cc < 16; ++cc) {
            float4 a4 = *(const float4*)&a_lds[c0 + cc][tn * 4];
            const float4* wr4 = (const float4*)&w_lds[cc][to * 8];
            float4 wa = wr4[0], wb = wr4[1];
            float wv[8] = {wa.x, wa.y, wa.z, wa.w, wb.x, wb.y, wb.z, wb.w};
            #pragma unroll
            for (int oj = 0; oj < 8; ++oj) {
                float wvv = wv[oj];
                acc[0][oj] += a4.x * wvv; acc[1][oj] += a4.y * wvv;
                acc[2][oj] += a4.z * wvv; acc[3][oj] += a4.w * wvv;
            }
        }
    }
    #pragma unroll
    for (int rr = 0; rr < 4; ++rr) {
        int n = nb + tn * 4 + rr;
        #pragma unroll
        for (int oj = 0; oj < 8; ++oj) {
            int o = to * 8 + oj;
            size_t addr = (size_t)(b * C_ + o) * N_ + n;
            out[addr] = acc[rr][oj] + b2[o] + b2f(x2[addr]);
        }
    }
}

extern "C" void kernel_launch(void* const* d_in, const int* in_sizes, int n_in,
                              void* d_out, int out_size, void* d_ws, size_t ws_size,
                              hipStream_t stream) {
    const float* x         = (const float*)d_in[0];
    const float* lth_dw_w  = (const float*)d_in[2];
    const float* lth_pw_w  = (const float*)d_in[3];
    const float* lth_pw_b  = (const float*)d_in[4];
    const float* lth_gate_w= (const float*)d_in[5];
    const float* lth_gate_b= (const float*)d_in[6];
    const float* lth_scale = (const float*)d_in[7];
    const float* ln1_g     = (const float*)d_in[8];
    const float* ln1_b     = (const float*)d_in[9];
    const float* ln2_g     = (const float*)d_in[10];
    const float* ln2_b     = (const float*)d_in[11];
    const float* qkv_w     = (const float*)d_in[12];
    const float* gate_w    = (const float*)d_in[13];
    const float* gate_b    = (const float*)d_in[14];
    const float* proj_w    = (const float*)d_in[15];
    const float* pe_w      = (const float*)d_in[16];
    const float* pe_b      = (const float*)d_in[17];
    const float* fc1_w     = (const float*)d_in[18];
    const float* fc1_b     = (const float*)d_in[19];
    const float* dw_w      = (const float*)d_in[20];
    const float* dw_b      = (const float*)d_in[21];
    const float* fc2_w     = (const float*)d_in[22];
    const float* fc2_b     = (const float*)d_in[23];

    // Slab plan (bytes). Peak concurrent = 203,423,744 B (~194 MiB), lifetime-aliased.
    //  A @0        (32 MiB): x1 -> xn -> h2 (h2 spans A+B)
    //  B @32 MiB   (40.5)  : low+sg -> t2
    //  C @72.5 MiB (40.5)  : q -> x2
    //  D @113 MiB  (40.5)  : hf -> k -> h1 (h1 spans D+E)
    //  E @153.5 MiB(40.5)  : g -> v
    char* ws = (char*)d_ws;
    constexpr size_t SZ_X = 33554432;    // bf16, 16,777,216 elems
    constexpr size_t SZ_W = 42467328;    // bf16, 21,233,664 elems
    constexpr size_t OFF_A = 0;
    constexpr size_t OFF_B = OFF_A + SZ_X;
    constexpr size_t OFF_C = OFF_B + SZ_W;
    constexpr size_t OFF_D = OFF_C + SZ_W;
    constexpr size_t OFF_E = OFF_D + SZ_W;

    bf16*  x1  = (bf16*)(ws + OFF_A);
    bf16*  xn  = (bf16*)(ws + OFF_A);
    bf16*  h2  = (bf16*)(ws + OFF_A);   // 64 MiB, spans A+B
    float* low = (float*)(ws + OFF_B);  // 16 MiB
    float* sg  = (float*)(ws + OFF_B + 16777216);
    bf16*  t2  = (bf16*)(ws + OFF_B);
    bf16*  q   = (bf16*)(ws + OFF_C);
    bf16*  x2  = (bf16*)(ws + OFF_C);
    bf16*  hf  = (bf16*)(ws + OFF_D);
    bf16*  k   = (bf16*)(ws + OFF_D);
    bf16*  h1  = (bf16*)(ws + OFF_D);   // 64 MiB, spans D+E
    bf16*  g   = (bf16*)(ws + OFF_E);
    bf16*  v   = (bf16*)(ws + OFF_E);

    k_pool <<<16384, 256, 0, stream>>>(x, low);
    k_hf   <<<65536, 256, 0, stream>>>(x, low, hf);
    k_sgate<<<512,   256, 0, stream>>>(hf, lth_gate_w, lth_gate_b, sg);
    k_dw3  <<<65536, 256, 0, stream>>>(hf, lth_dw_w, g);
    k_pw   <<<2048,  256, 0, stream>>>(g, lth_pw_w, lth_pw_b, x, lth_scale, sg, x1);
    k_qkv  <<<2592,  256, 0, stream>>>(x1, ln1_g, ln1_b, qkv_w, q, k, v);
    k_attn <<<2592,  256, 0, stream>>>(x1, q, k, v, ln1_g, ln1_b, gate_w, gate_b, pe_w, pe_b, proj_w, t2);
    k_fold <<<65536, 256, 0, stream>>>(t2, x2);
    k_ln2  <<<512,   256, 0, stream>>>(x2, ln2_g, ln2_b, xn);
    k_fc1  <<<2048,  256, 0, stream>>>(xn, fc1_w, fc1_b, h1);
    k_dw5  <<<131072,256, 0, stream>>>(h1, dw_w, dw_b, h2);
    k_fc2  <<<2048,  256, 0, stream>>>(h2, fc2_w, fc2_b, x2, (float*)d_out);
}

// Round 3
// 21464.796 us; speedup vs baseline: 1.0270x; 1.0270x over previous
//
#include <hip/hip_runtime.h>
#include <hip/hip_bf16.h>
#include <math.h>

typedef __hip_bfloat16 bf16;
typedef __attribute__((ext_vector_type(8))) short bf16x8;
typedef __attribute__((ext_vector_type(4))) float f32x4;

static constexpr int B_ = 8, C_ = 128, H_ = 128, W_ = 128;
static constexpr int N_ = H_ * W_;          // 16384
static constexpr int NWIN = 648;            // B * 9 * 9

__device__ __forceinline__ float b2f(bf16 v) { return __bfloat162float(v); }
__device__ __forceinline__ bf16 f2b(float v) { return __float2bfloat16(v); }
__device__ __forceinline__ float gelu_f(float x) {
    return 0.5f * x * (1.0f + erff(x * 0.70710678118654752f));
}

// ---------------- K1: 2x2 avg pool (fp32) ----------------
__global__ __launch_bounds__(256) void k_pool(const float* __restrict__ x, float* __restrict__ low) {
    int idx = blockIdx.x * 256 + threadIdx.x;       // 4,194,304
    int j = idx & 63, i = (idx >> 6) & 63, bc = idx >> 12;
    const float* p = x + (size_t)bc * N_ + (i * 2) * W_ + j * 2;
    low[idx] = (p[0] + p[1] + p[W_] + p[W_ + 1]) * 0.25f;
}

// ---------------- K2: hf = x - bilinear_up(low)  (bf16 out) ----------------
__global__ __launch_bounds__(256) void k_hf(const float* __restrict__ x, const float* __restrict__ low,
                                            bf16* __restrict__ hf) {
    int idx = blockIdx.x * 256 + threadIdx.x;       // 16,777,216
    int w = idx & 127, h = (idx >> 7) & 127, bc = idx >> 14;
    int jh = h >> 1, jw = w >> 1;
    int h0, h1; float wh0, wh1;
    if (h & 1) { h0 = jh; h1 = jh + 1 > 63 ? 63 : jh + 1; wh0 = 0.75f; wh1 = 0.25f; }
    else       { h0 = jh - 1 < 0 ? 0 : jh - 1; h1 = jh;   wh0 = 0.25f; wh1 = 0.75f; }
    int w0, w1; float ww0, ww1;
    if (w & 1) { w0 = jw; w1 = jw + 1 > 63 ? 63 : jw + 1; ww0 = 0.75f; ww1 = 0.25f; }
    else       { w0 = jw - 1 < 0 ? 0 : jw - 1; w1 = jw;   ww0 = 0.25f; ww1 = 0.75f; }
    const float* lp = low + (size_t)bc * 4096;
    float up = wh0 * (ww0 * lp[h0 * 64 + w0] + ww1 * lp[h0 * 64 + w1])
             + wh1 * (ww0 * lp[h1 * 64 + w0] + ww1 * lp[h1 * 64 + w1]);
    hf[idx] = f2b(x[idx] - up);
}

// ---------------- K3: sgate (fp32 out) ----------------
__global__ __launch_bounds__(256) void k_sgate(const bf16* __restrict__ hf, const float* __restrict__ gw,
                                               const float* __restrict__ gb, float* __restrict__ sg) {
    int idx = blockIdx.x * 256 + threadIdx.x;       // 131072
    int n = idx & (N_ - 1); int b = idx >> 14;
    const bf16* p = hf + (size_t)b * C_ * N_ + n;
    float s = 0.f;
    for (int c = 0; c < C_; ++c) s += gw[c] * fabsf(b2f(p[(size_t)c * N_]));
    s += gb[0];
    sg[idx] = 1.0f / (1.0f + expf(-s));
}

// ---------------- K4: g = gelu(dwconv3x3 dil2) (bf16) ----------------
__global__ __launch_bounds__(256) void k_dw3(const bf16* __restrict__ hf, const float* __restrict__ wdw,
                                             bf16* __restrict__ g) {
    int idx = blockIdx.x * 256 + threadIdx.x;
    int w = idx & 127, h = (idx >> 7) & 127, bc = idx >> 14, c = bc & 127;
    const bf16* p = hf + (size_t)bc * N_;
    const float* kw = wdw + c * 9;
    float s = 0.f;
    #pragma unroll
    for (int ky = 0; ky < 3; ++ky) {
        int hh = h + (ky - 1) * 2;
        if ((unsigned)hh >= 128u) continue;
        #pragma unroll
        for (int kx = 0; kx < 3; ++kx) {
            int ww = w + (kx - 1) * 2;
            if ((unsigned)ww >= 128u) continue;
            s += kw[ky * 3 + kx] * b2f(p[hh * W_ + ww]);
        }
    }
    g[idx] = f2b(gelu_f(s));
}

// ---------------- K5: pw GEMM + LTH epilogue -> x1 (bf16) ----------------
__global__ __launch_bounds__(256) void k_pw(const bf16* __restrict__ g, const float* __restrict__ pww,
                                            const float* __restrict__ pwb, const float* __restrict__ x,
                                            const float* __restrict__ scale, const float* __restrict__ sg,
                                            bf16* __restrict__ x1) {
    __shared__ __align__(16) float a_lds[128][64];
    __shared__ __align__(16) float w_lds[16][128];
    int tid = threadIdx.x;
    int gtok = blockIdx.x * 64; int b = gtok >> 14; int nb = gtok & (N_ - 1);
    const bf16* A = g + (size_t)b * C_ * N_ + nb;
    for (int e = tid; e < 8192; e += 256) { int c = e >> 6, i = e & 63; a_lds[c][i] = b2f(A[(size_t)c * N_ + i]); }
    int tn = tid & 15, to = tid >> 4;
    float acc[4][8] = {};
    for (int c0 = 0; c0 < 128; c0 += 16) {
        __syncthreads();
        for (int e = tid; e < 2048; e += 256) { int cc = e & 15, o = e >> 4; w_lds[cc][o] = pww[o * 128 + c0 + cc]; }
        __syncthreads();
        for (int cc = 0; cc < 16; ++cc) {
            float4 a4 = *(const float4*)&a_lds[c0 + cc][tn * 4];
            const float4* wr4 = (const float4*)&w_lds[cc][to * 8];
            float4 wa = wr4[0], wb = wr4[1];
            float wv[8] = {wa.x, wa.y, wa.z, wa.w, wb.x, wb.y, wb.z, wb.w};
            #pragma unroll
            for (int oj = 0; oj < 8; ++oj) {
                float wvv = wv[oj];
                acc[0][oj] += a4.x * wvv; acc[1][oj] += a4.y * wvv;
                acc[2][oj] += a4.z * wvv; acc[3][oj] += a4.w * wvv;
            }
        }
    }
    #pragma unroll
    for (int rr = 0; rr < 4; ++rr) {
        int n = nb + tn * 4 + rr;
        float sgv = sg[(b << 14) + n];
        #pragma unroll
        for (int oj = 0; oj < 8; ++oj) {
            int o = to * 8 + oj;
            size_t oaddr = (size_t)(b * C_ + o) * N_ + n;
            x1[oaddr] = f2b(x[oaddr] + scale[o] * (acc[rr][oj] + pwb[o]) * sgv);
        }
    }
}

// ---------------- K6: fused LN1 + qkv GEMM -> q,k [tok][c], v [c][tok] (bf16) ----------------
__global__ __launch_bounds__(256) void k_qkv(const bf16* __restrict__ x1, const float* __restrict__ lng,
                                             const float* __restrict__ lnb, const float* __restrict__ qkvw,
                                             bf16* __restrict__ q, bf16* __restrict__ k, bf16* __restrict__ v) {
    __shared__ __align__(16) float y_lds[128][64];
    __shared__ __align__(16) float w_lds[16][128];
    __shared__ float red2[8][64];
    __shared__ float mu_l[64], rs_l[64];
    int tid = threadIdx.x;
    int win = blockIdx.x >> 2; int tokbase = (blockIdx.x & 3) * 64;
    int b = win / 81; int r0 = win % 81; int top = (r0 / 9) * 14, left = (r0 % 9) * 14;
    for (int e = tid; e < 8192; e += 256) {
        int c = e >> 6, i = e & 63; int tok = tokbase + i; int p = tok >> 4, qq = tok & 15;
        y_lds[c][i] = b2f(x1[(size_t)(b * C_ + c) * N_ + (top + p) * W_ + (left + qq)]);
    }
    __syncthreads();
    { // LN stats: 4 partials per token
        int i = tid & 63, r = tid >> 6;
        float s = 0.f, ss = 0.f;
        for (int cc = r * 32; cc < r * 32 + 32; ++cc) { float vv = y_lds[cc][i]; s += vv; ss += vv * vv; }
        red2[r][i] = s; red2[4 + r][i] = ss;
    }
    __syncthreads();
    if (tid < 64) {
        float s = red2[0][tid] + red2[1][tid] + red2[2][tid] + red2[3][tid];
        float ss = red2[4][tid] + red2[5][tid] + red2[6][tid] + red2[7][tid];
        float mu = s * (1.f / 128.f); float var = ss * (1.f / 128.f) - mu * mu;
        mu_l[tid] = mu; rs_l[tid] = rsqrtf(var + 1e-6f);
    }
    __syncthreads();
    for (int e = tid; e < 8192; e += 256) {
        int c = e >> 6, i = e & 63;
        y_lds[c][i] = (y_lds[c][i] - mu_l[i]) * rs_l[i] * lng[c] + lnb[c];
    }
    int tn = tid & 15, to = tid >> 4;
    for (int pass = 0; pass < 3; ++pass) {
        float acc[4][8] = {};
        for (int c0 = 0; c0 < 128; c0 += 16) {
            __syncthreads();
            for (int e = tid; e < 2048; e += 256) { int cc = e >> 7, o = e & 127; w_lds[cc][o] = qkvw[(c0 + cc) * 384 + pass * 128 + o]; }
            __syncthreads();
            for (int cc = 0; cc < 16; ++cc) {
                float4 a4 = *(const float4*)&y_lds[c0 + cc][tn * 4];
                const float4* wr4 = (const float4*)&w_lds[cc][to * 8];
                float4 wa = wr4[0], wb = wr4[1];
                float wv[8] = {wa.x, wa.y, wa.z, wa.w, wb.x, wb.y, wb.z, wb.w};
                #pragma unroll
                for (int oj = 0; oj < 8; ++oj) {
                    float wvv = wv[oj];
                    acc[0][oj] += a4.x * wvv; acc[1][oj] += a4.y * wvv;
                    acc[2][oj] += a4.z * wvv; acc[3][oj] += a4.w * wvv;
                }
            }
        }
        if (pass < 2) {
            bf16* outp = (pass == 0) ? q : k;      // [win][tok][c]
            #pragma unroll
            for (int rr = 0; rr < 4; ++rr) {
                int tok = tokbase + tn * 4 + rr;
                union { bf16 h[8]; uint4 u; } tmp;
                #pragma unroll
                for (int oj = 0; oj < 8; ++oj) tmp.h[oj] = f2b(acc[rr][oj]);
                *(uint4*)(outp + ((size_t)win * 256 + tok) * 128 + to * 8) = tmp.u;
            }
        } else {                                    // v: [win][c][tok]
            #pragma unroll
            for (int rr = 0; rr < 4; ++rr) {
                int tok = tokbase + tn * 4 + rr;
                #pragma unroll
                for (int oj = 0; oj < 8; ++oj)
                    v[(size_t)win * 32768 + (size_t)(to * 8 + oj) * 256 + tok] = f2b(acc[rr][oj]);
            }
        }
        __syncthreads();
    }
}

// ---------------- K7: MFMA attention core: softmax(QK^T*scale)V -> o [win][tok][c] ----------------
// Block = one window-quarter (64 q-rows). 4 waves; wave w owns q-rows [w*16, w*16+16).
__global__ __launch_bounds__(256) void k_attn_mfma(const bf16* __restrict__ qb, const bf16* __restrict__ kb,
                                                   const bf16* __restrict__ vb, bf16* __restrict__ ob) {
    __shared__ __align__(16) char lds[49152];   // [0,32K): q (16K, scores phase) then P (32K); [32K,48K): K/V chunk
    int tid = threadIdx.x;
    int lane = tid & 63, w = tid >> 6;
    int l15 = lane & 15, lhi = lane >> 4;
    int win = blockIdx.x >> 2, qbase = (blockIdx.x & 3) * 64;
    const bf16* qg = qb + ((size_t)win * 256 + qbase) * 128;   // [64][128]
    const bf16* kg = kb + (size_t)win * 256 * 128;             // [256][128]
    const bf16* vg = vb + (size_t)win * 128 * 256;             // [128][256]
    char* chunk = lds + 32768;
    // stage q tile [64 rows][256B], XOR-swizzled
    for (int e = tid; e < 1024; e += 256) {
        int row = e >> 4, slot = e & 15;
        uint4 val = *(const uint4*)((const char*)qg + row * 256 + slot * 16);
        *(uint4*)(lds + row * 256 + ((slot * 16) ^ ((row & 7) << 4))) = val;
    }
    __syncthreads();
    // hoist A-frags (q rows w*16 + l15, 4 c-chunks of 32)
    bf16x8 afr[4];
    {
        int row = w * 16 + l15;
        #pragma unroll
        for (int cc = 0; cc < 4; ++cc) {
            int cb = cc * 64 + lhi * 16;
            afr[cc] = *(const bf16x8*)(lds + row * 256 + (cb ^ ((row & 7) << 4)));
        }
    }
    f32x4 acc[16];
    #pragma unroll
    for (int t = 0; t < 16; ++t) acc[t] = (f32x4){0.f, 0.f, 0.f, 0.f};
    // ---- scores: 4 key-chunks of 64 ----
    for (int kc = 0; kc < 4; ++kc) {
        __syncthreads();
        for (int e = tid; e < 1024; e += 256) {
            int row = e >> 4, slot = e & 15;
            uint4 val = *(const uint4*)((const char*)kg + (size_t)(kc * 64 + row) * 256 + slot * 16);
            *(uint4*)(chunk + row * 256 + ((slot * 16) ^ ((row & 7) << 4))) = val;
        }
        __syncthreads();
        #pragma unroll
        for (int t = 0; t < 4; ++t) {
            int row = t * 16 + l15;
            #pragma unroll
            for (int cc = 0; cc < 4; ++cc) {
                int cb = cc * 64 + lhi * 16;
                bf16x8 bfr = *(const bf16x8*)(chunk + row * 256 + (cb ^ ((row & 7) << 4)));
                acc[kc * 4 + t] = __builtin_amdgcn_mfma_f32_16x16x32_bf16(afr[cc], bfr, acc[kc * 4 + t], 0, 0, 0);
            }
        }
    }
    // ---- softmax (rows = w*16 + lhi*4 + r; cols = t*16 + l15), in-wave ----
    const float sm_scale = 0.08838834764831845f;   // 128^-0.5
    #pragma unroll
    for (int r = 0; r < 4; ++r) {
        float m = -1e30f;
        #pragma unroll
        for (int t = 0; t < 16; ++t) m = fmaxf(m, acc[t][r]);
        #pragma unroll
        for (int d2 = 1; d2 < 16; d2 <<= 1) m = fmaxf(m, __shfl_xor(m, d2, 64));
        float ssum = 0.f;
        #pragma unroll
        for (int t = 0; t < 16; ++t) { float p = __expf((acc[t][r] - m) * sm_scale); acc[t][r] = p; ssum += p; }
        #pragma unroll
        for (int d2 = 1; d2 < 16; d2 <<= 1) ssum += __shfl_xor(ssum, d2, 64);
        float inv = 1.f / ssum;
        #pragma unroll
        for (int t = 0; t < 16; ++t) acc[t][r] *= inv;
    }
    // write P [64 rows][512B] bf16, swizzled (overlaps dead q region; a-frags already in regs)
    #pragma unroll
    for (int t = 0; t < 16; ++t) {
        #pragma unroll
        for (int r = 0; r < 4; ++r) {
            int row = w * 16 + lhi * 4 + r;
            int cb = (t * 16 + l15) * 2;
            *(bf16*)(lds + row * 512 + (cb ^ ((row & 7) << 4))) = f2b(acc[t][r]);
        }
    }
    // ---- PV: 4 key-chunks of 64 ----
    f32x4 oacc[8];
    #pragma unroll
    for (int t = 0; t < 8; ++t) oacc[t] = (f32x4){0.f, 0.f, 0.f, 0.f};
    for (int vc = 0; vc < 4; ++vc) {
        __syncthreads();
        for (int e = tid; e < 1024; e += 256) {
            int row = e >> 3, slot = e & 7;   // c-row, 128B of keys
            uint4 val = *(const uint4*)((const char*)vg + (size_t)row * 512 + vc * 128 + slot * 16);
            *(uint4*)(chunk + row * 128 + ((slot * 16) ^ ((row & 7) << 4))) = val;
        }
        __syncthreads();
        #pragma unroll
        for (int jc = 0; jc < 2; ++jc) {
            int prow = w * 16 + l15;
            int pcb = vc * 128 + jc * 64 + lhi * 16;
            bf16x8 ap = *(const bf16x8*)(lds + prow * 512 + (pcb ^ ((prow & 7) << 4)));
            #pragma unroll
            for (int ct = 0; ct < 8; ++ct) {
                int vrow = ct * 16 + l15;
                int vcb = jc * 64 + lhi * 16;
                bf16x8 bv = *(const bf16x8*)(chunk + vrow * 128 + (vcb ^ ((vrow & 7) << 4)));
                oacc[ct] = __builtin_amdgcn_mfma_f32_16x16x32_bf16(ap, bv, oacc[ct], 0, 0, 0);
            }
        }
    }
    // write o [win][tok][c]
    bf16* og = ob + ((size_t)win * 256 + qbase) * 128;
    #pragma unroll
    for (int ct = 0; ct < 8; ++ct) {
        #pragma unroll
        for (int r = 0; r < 4; ++r) {
            int row = w * 16 + lhi * 4 + r;
            og[row * 128 + ct * 16 + l15] = f2b(oacc[ct][r]);
        }
    }
}

// ---------------- K8: LN1 + gate-z + PE + proj + residual -> t2 [win][c][tok] (bf16) ----------------
__global__ __launch_bounds__(256) void k_pepr(const bf16* __restrict__ ob, const bf16* __restrict__ qb,
                                              const bf16* __restrict__ x1,
                                              const float* __restrict__ lng, const float* __restrict__ lnb,
                                              const float* __restrict__ gatew, const float* __restrict__ gateb,
                                              const float* __restrict__ pew, const float* __restrict__ peb,
                                              const float* __restrict__ projw, bf16* __restrict__ t2) {
    __shared__ __align__(16) float y_lds[128][64];     // LN -> z -> gated A
    __shared__ __align__(16) float w_lds[16][128];
    __shared__ __align__(16) bf16 xt_lds[128][64];
    __shared__ float red2[8][64];
    __shared__ float mu_l[64], rs_l[64];
    int tid = threadIdx.x;
    int win = blockIdx.x >> 2; int qbase = (blockIdx.x & 3) * 64;
    int b = win / 81; int r0 = win % 81; int top = (r0 / 9) * 14, left = (r0 % 9) * 14;
    for (int e = tid; e < 8192; e += 256) {
        int c = e >> 6, i = e & 63; int tok = qbase + i; int p = tok >> 4, qq = tok & 15;
        xt_lds[c][i] = x1[(size_t)(b * C_ + c) * N_ + (top + p) * W_ + (left + qq)];
    }
    __syncthreads();
    { // LN stats
        int i = tid & 63, r = tid >> 6;
        float s = 0.f, ss = 0.f;
        for (int cc = r * 32; cc < r * 32 + 32; ++cc) { float vv = b2f(xt_lds[cc][i]); s += vv; ss += vv * vv; }
        red2[r][i] = s; red2[4 + r][i] = ss;
    }
    __syncthreads();
    if (tid < 64) {
        float s = red2[0][tid] + red2[1][tid] + red2[2][tid] + red2[3][tid];
        float ss = red2[4][tid] + red2[5][tid] + red2[6][tid] + red2[7][tid];
        float mu = s * (1.f / 128.f); float var = ss * (1.f / 128.f) - mu * mu;
        mu_l[tid] = mu; rs_l[tid] = rsqrtf(var + 1e-6f);
    }
    __syncthreads();
    for (int e = tid; e < 8192; e += 256) {
        int c = e >> 6, i = e & 63;
        y_lds[c][i] = (b2f(xt_lds[c][i]) - mu_l[i]) * rs_l[i] * lng[c] + lnb[c];
    }
    int tn = tid & 15, to = tid >> 4;
    // ---- z = gelu(y @ gate_w + gate_b) ----
    float zv[4][8] = {};
    for (int c0 = 0; c0 < 128; c0 += 16) {
        __syncthreads();
        for (int e = tid; e < 2048; e += 256) { int cc = e >> 7, o = e & 127; w_lds[cc][o] = gatew[(c0 + cc) * 128 + o]; }
        __syncthreads();
        for (int cc = 0; cc < 16; ++cc) {
            float4 a4 = *(const float4*)&y_lds[c0 + cc][tn * 4];
            const float4* wr4 = (const float4*)&w_lds[cc][to * 8];
            float4 wa = wr4[0], wb = wr4[1];
            float wv[8] = {wa.x, wa.y, wa.z, wa.w, wb.x, wb.y, wb.z, wb.w};
            #pragma unroll
            for (int oj = 0; oj < 8; ++oj) {
                float wvv = wv[oj];
                zv[0][oj] += a4.x * wvv; zv[1][oj] += a4.y * wvv;
                zv[2][oj] += a4.z * wvv; zv[3][oj] += a4.w * wvv;
            }
        }
    }
    __syncthreads();   // all y_lds reads done
    #pragma unroll
    for (int rr = 0; rr < 4; ++rr)
        #pragma unroll
        for (int oj = 0; oj < 8; ++oj)
            y_lds[to * 8 + oj][tn * 4 + rr] = gelu_f(zv[rr][oj] + gateb[to * 8 + oj]);
    __syncthreads();
    // ---- PE + gate: thread = (tok, c-group of 32); wave-uniform channel group ----
    {
        int tok = tid & 63, cg = tid >> 6;
        int gtok = qbase + tok; int pp = gtok >> 4, qq = gtok & 15;
        const bf16* oq = ob + ((size_t)win * 256 + gtok) * 128 + cg * 32;
        float pv[32];
        #pragma unroll
        for (int cc = 0; cc < 32; ++cc) pv[cc] = peb[cg * 32 + cc];
        #pragma unroll
        for (int ky = 0; ky < 3; ++ky) {
            int py = pp + ky - 1; if ((unsigned)py >= 16u) continue;
            #pragma unroll
            for (int kx = 0; kx < 3; ++kx) {
                int qx = qq + kx - 1; if ((unsigned)qx >= 16u) continue;
                const bf16* qrow = qb + ((size_t)win * 256 + py * 16 + qx) * 128 + cg * 32;
                #pragma unroll
                for (int cc = 0; cc < 32; ++cc)
                    pv[cc] += pew[(cg * 32 + cc) * 9 + ky * 3 + kx] * b2f(qrow[cc]);
            }
        }
        #pragma unroll
        for (int cc = 0; cc < 32; ++cc) {
            int c = cg * 32 + cc;
            float zval = y_lds[c][tok];
            y_lds[c][tok] = (b2f(oq[cc]) + pv[cc]) * zval;
        }
    }
    // ---- proj GEMM + crop residual -> t2 ----
    float pacc[4][8] = {};
    for (int c0 = 0; c0 < 128; c0 += 16) {
        __syncthreads();
        for (int e = tid; e < 2048; e += 256) { int cc = e >> 7, o = e & 127; w_lds[cc][o] = projw[(c0 + cc) * 128 + o]; }
        __syncthreads();
        for (int cc = 0; cc < 16; ++cc) {
            float4 a4 = *(const float4*)&y_lds[c0 + cc][tn * 4];
            const float4* wr4 = (const float4*)&w_lds[cc][to * 8];
            float4 wa = wr4[0], wb = wr4[1];
            float wv[8] = {wa.x, wa.y, wa.z, wa.w, wb.x, wb.y, wb.z, wb.w};
            #pragma unroll
            for (int oj = 0; oj < 8; ++oj) {
                float wvv = wv[oj];
                pacc[0][oj] += a4.x * wvv; pacc[1][oj] += a4.y * wvv;
                pacc[2][oj] += a4.z * wvv; pacc[3][oj] += a4.w * wvv;
            }
        }
    }
    #pragma unroll
    for (int rr = 0; rr < 4; ++rr) {
        int tok = qbase + tn * 4 + rr;
        #pragma unroll
        for (int oj = 0; oj < 8; ++oj) {
            int o = to * 8 + oj;
            t2[(size_t)win * 32768 + (size_t)o * 256 + tok] = f2b(pacc[rr][oj] + b2f(xt_lds[o][tn * 4 + rr]));
        }
    }
}

// ---------------- K9: overlap-fold with divisor -> x2 (bf16) ----------------
__global__ __launch_bounds__(256) void k_fold(const bf16* __restrict__ t2, bf16* __restrict__ x2) {
    int idx = blockIdx.x * 256 + threadIdx.x;      // 16,777,216
    int w = idx & 127, h = (idx >> 7) & 127, c = (idx >> 14) & 127, b = idx >> 21;
    int imin = (h < 16) ? 0 : (h - 2) / 14; int imax = h / 14; if (imax > 8) imax = 8;
    int jmin = (w < 16) ? 0 : (w - 2) / 14; int jmax = w / 14; if (jmax > 8) jmax = 8;
    float sum = 0.f;
    for (int i = imin; i <= imax; ++i)
        for (int j = jmin; j <= jmax; ++j) {
            int win = (b * 9 + i) * 9 + j;
            sum += b2f(t2[(size_t)win * 32768 + c * 256 + (h - i * 14) * 16 + (w - j * 14)]);
        }
    int cnt = (imax - imin + 1) * (jmax - jmin + 1);
    x2[idx] = f2b(sum / (float)cnt);
}

// ---------------- K10: LN2 -> xn (bf16) ----------------
__global__ __launch_bounds__(256) void k_ln2(const bf16* __restrict__ x2, const float* __restrict__ gam,
                                             const float* __restrict__ bet, bf16* __restrict__ xn) {
    int idx = blockIdx.x * 256 + threadIdx.x;      // 131072
    int n = idx & (N_ - 1); int b = idx >> 14;
    const bf16* p = x2 + (size_t)b * C_ * N_ + n;
    float s = 0.f, ss = 0.f;
    for (int c = 0; c < C_; ++c) { float v = b2f(p[(size_t)c * N_]); s += v; ss += v * v; }
    float mu = s * (1.f / 128.f);
    float var = ss * (1.f / 128.f) - mu * mu;
    float rs = rsqrtf(var + 1e-6f);
    bf16* o = xn + (size_t)b * C_ * N_ + n;
    for (int c = 0; c < C_; ++c) o[(size_t)c * N_] = f2b((b2f(p[(size_t)c * N_]) - mu) * rs * gam[c] + bet[c]);
}

// ---------------- K11: fc1 GEMM + gelu -> h1 (bf16) ----------------
__global__ __launch_bounds__(256) void k_fc1(const bf16* __restrict__ xn, const float* __restrict__ w1,
                                             const float* __restrict__ b1, bf16* __restrict__ h1) {
    __shared__ __align__(16) float a_lds[128][64];
    __shared__ __align__(16) float w_lds[16][256];
    int tid = threadIdx.x;
    int gtok = blockIdx.x * 64; int b = gtok >> 14; int nb = gtok & (N_ - 1);
    const bf16* A = xn + (size_t)b * C_ * N_ + nb;
    for (int e = tid; e < 8192; e += 256) { int c = e >> 6, i = e & 63; a_lds[c][i] = b2f(A[(size_t)c * N_ + i]); }
    int tn = tid & 15, to = tid >> 4;
    float acc[4][16] = {};
    for (int c0 = 0; c0 < 128; c0 += 16) {
        __syncthreads();
        for (int e = tid; e < 4096; e += 256) { int cc = e >> 8, o = e & 255; w_lds[cc][o] = w1[(c0 + cc) * 256 + o]; }
        __syncthreads();
        for (int cc = 0; cc < 16; ++cc) {
            float4 a4 = *(const float4*)&a_lds[c0 + cc][tn * 4];
            const float4* wr4 = (const float4*)&w_lds[cc][to * 16];
            float4 w0 = wr4[0], w1v = wr4[1], w2 = wr4[2], w3 = wr4[3];
            float wv[16] = {w0.x, w0.y, w0.z, w0.w, w1v.x, w1v.y, w1v.z, w1v.w,
                            w2.x, w2.y, w2.z, w2.w, w3.x, w3.y, w3.z, w3.w};
            #pragma unroll
            for (int oj = 0; oj < 16; ++oj) {
                float wvv = wv[oj];
                acc[0][oj] += a4.x * wvv; acc[1][oj] += a4.y * wvv;
                acc[2][oj] += a4.z * wvv; acc[3][oj] += a4.w * wvv;
            }
        }
    }
    #pragma unroll
    for (int rr = 0; rr < 4; ++rr) {
        int n = nb + tn * 4 + rr;
        #pragma unroll
        for (int oj = 0; oj < 16; ++oj) {
            int o = to * 16 + oj;
            h1[(size_t)(b * 256 + o) * N_ + n] = f2b(gelu_f(acc[rr][oj] + b1[o]));
        }
    }
}

// ---------------- K12: h2 = h1 + dwconv5x5(h1) + dw_b (bf16) ----------------
__global__ __launch_bounds__(256) void k_dw5(const bf16* __restrict__ h1, const float* __restrict__ wdw,
                                             const float* __restrict__ bdw, bf16* __restrict__ h2) {
    int idx = blockIdx.x * 256 + threadIdx.x;      // 33,554,432
    int w = idx & 127, h = (idx >> 7) & 127, ch = (idx >> 14) & 255, b = idx >> 22;
    const bf16* p = h1 + (size_t)(b * 256 + ch) * N_;
    const float* kw = wdw + ch * 25;
    float s = 0.f;
    #pragma unroll
    for (int ky = 0; ky < 5; ++ky) {
        int hh = h + ky - 2;
        if ((unsigned)hh >= 128u) continue;
        #pragma unroll
        for (int kx = 0; kx < 5; ++kx) {
            int ww = w + kx - 2;
            if ((unsigned)ww >= 128u) continue;
            s += kw[ky * 5 + kx] * b2f(p[hh * W_ + ww]);
        }
    }
    h2[idx] = f2b(b2f(p[h * W_ + w]) + s + bdw[ch]);
}

// ---------------- K13: fc2 GEMM + bias + residual -> d_out (fp32) ----------------
__global__ __launch_bounds__(256) void k_fc2(const bf16* __restrict__ h2, const float* __restrict__ w2,
                                             const float* __restrict__ b2, const bf16* __restrict__ x2,
                                             float* __restrict__ out) {
    __shared__ __align__(16) float a_lds[256][64];
    __shared__ __align__(16) float w_lds[16][128];
    int tid = threadIdx.x;
    int gtok = blockIdx.x * 64; int b = gtok >> 14; int nb = gtok & (N_ - 1);
    const bf16* A = h2 + (size_t)b * 256 * N_ + nb;
    for (int e = tid; e < 16384; e += 256) { int c = e >> 6, i = e & 63; a_lds[c][i] = b2f(A[(size_t)c * N_ + i]); }
    int tn = tid & 15, to = tid >> 4;
    float acc[4][8] = {};
    for (int c0 = 0; c0 < 256; c0 += 16) {
        __syncthreads();
        for (int e = tid; e < 2048; e += 256) { int cc = e >> 7, o = e & 127; w_lds[cc][o] = w2[(c0 + cc) * 128 + o]; }
        __syncthreads();
        for (int cc = 0; cc < 16; ++cc) {
            float4 a4 = *(const float4*)&a_lds[c0 + cc][tn * 4];
            const float4* wr4 = (const float4*)&w_lds[cc][to * 8];
            float4 wa = wr4[0], wb = wr4[1];
            float wv[8] = {wa.x, wa.y, wa.z, wa.w, wb.x, wb.y, wb.z, wb.w};
            #pragma unroll
            for (int oj = 0; oj < 8; ++oj) {
                float wvv = wv[oj];
                acc[0][oj] += a4.x * wvv; acc[1][oj] += a4.y * wvv;
                acc[2][oj] += a4.z * wvv; acc[3][oj] += a4.w * wvv;
            }
        }
    }
    #pragma unroll
    for (int rr = 0; rr < 4; ++rr) {
        int n = nb + tn * 4 + rr;
        #pragma unroll
        for (int oj = 0; oj < 8; ++oj) {
            int o = to * 8 + oj;
            size_t addr = (size_t)(b * C_ + o) * N_ + n;
            out[addr] = acc[rr][oj] + b2[o] + b2f(x2[addr]);
        }
    }
}

extern "C" void kernel_launch(void* const* d_in, const int* in_sizes, int n_in,
                              void* d_out, int out_size, void* d_ws, size_t ws_size,
                              hipStream_t stream) {
    const float* x         = (const float*)d_in[0];
    const float* lth_dw_w  = (const float*)d_in[2];
    const float* lth_pw_w  = (const float*)d_in[3];
    const float* lth_pw_b  = (const float*)d_in[4];
    const float* lth_gate_w= (const float*)d_in[5];
    const float* lth_gate_b= (const float*)d_in[6];
    const float* lth_scale = (const float*)d_in[7];
    const float* ln1_g     = (const float*)d_in[8];
    const float* ln1_b     = (const float*)d_in[9];
    const float* ln2_g     = (const float*)d_in[10];
    const float* ln2_b     = (const float*)d_in[11];
    const float* qkv_w     = (const float*)d_in[12];
    const float* gate_w    = (const float*)d_in[13];
    const float* gate_b    = (const float*)d_in[14];
    const float* proj_w    = (const float*)d_in[15];
    const float* pe_w      = (const float*)d_in[16];
    const float* pe_b      = (const float*)d_in[17];
    const float* fc1_w     = (const float*)d_in[18];
    const float* fc1_b     = (const float*)d_in[19];
    const float* dw_w      = (const float*)d_in[20];
    const float* dw_b      = (const float*)d_in[21];
    const float* fc2_w     = (const float*)d_in[22];
    const float* fc2_b     = (const float*)d_in[23];

    // Slab plan (bytes), peak 194 MiB (same as round 2, proven):
    //  A @0      (32 MiB)  : x1 -> xn ; h2 spans A+B
    //  B @A+32M  (40.5 MiB): low+sg -> o
    //  C @B+40.5 (40.5 MiB): q -> x2
    //  D @C+40.5 (40.5 MiB): hf -> k -> t2 ; h1 spans D+E
    //  E @D+40.5 (40.5 MiB): g -> v
    char* ws = (char*)d_ws;
    constexpr size_t SZ_X = 33554432;    // bf16, 16,777,216 elems
    constexpr size_t SZ_W = 42467328;    // bf16, 21,233,664 elems
    constexpr size_t OFF_A = 0;
    constexpr size_t OFF_B = OFF_A + SZ_X;
    constexpr size_t OFF_C = OFF_B + SZ_W;
    constexpr size_t OFF_D = OFF_C + SZ_W;
    constexpr size_t OFF_E = OFF_D + SZ_W;

    bf16*  x1  = (bf16*)(ws + OFF_A);
    bf16*  xn  = (bf16*)(ws + OFF_A);
    bf16*  h2  = (bf16*)(ws + OFF_A);   // spans A+B
    float* low = (float*)(ws + OFF_B);
    float* sg  = (float*)(ws + OFF_B + 16777216);
    bf16*  o   = (bf16*)(ws + OFF_B);
    bf16*  q   = (bf16*)(ws + OFF_C);
    bf16*  x2  = (bf16*)(ws + OFF_C);
    bf16*  hf  = (bf16*)(ws + OFF_D);
    bf16*  k   = (bf16*)(ws + OFF_D);
    bf16*  t2  = (bf16*)(ws + OFF_D);
    bf16*  h1  = (bf16*)(ws + OFF_D);   // spans D+E
    bf16*  g   = (bf16*)(ws + OFF_E);
    bf16*  v   = (bf16*)(ws + OFF_E);

    k_pool    <<<16384, 256, 0, stream>>>(x, low);
    k_hf      <<<65536, 256, 0, stream>>>(x, low, hf);
    k_sgate   <<<512,   256, 0, stream>>>(hf, lth_gate_w, lth_gate_b, sg);
    k_dw3     <<<65536, 256, 0, stream>>>(hf, lth_dw_w, g);
    k_pw      <<<2048,  256, 0, stream>>>(g, lth_pw_w, lth_pw_b, x, lth_scale, sg, x1);
    k_qkv     <<<2592,  256, 0, stream>>>(x1, ln1_g, ln1_b, qkv_w, q, k, v);
    k_attn_mfma<<<2592, 256, 0, stream>>>(q, k, v, o);
    k_pepr    <<<2592,  256, 0, stream>>>(o, q, x1, ln1_g, ln1_b, gate_w, gate_b, pe_w, pe_b, proj_w, t2);
    k_fold    <<<65536, 256, 0, stream>>>(t2, x2);
    k_ln2     <<<512,   256, 0, stream>>>(x2, ln2_g, ln2_b, xn);
    k_fc1     <<<2048,  256, 0, stream>>>(xn, fc1_w, fc1_b, h1);
    k_dw5     <<<131072,256, 0, stream>>>(h1, dw_w, dw_b, h2);
    k_fc2     <<<2048,  256, 0, stream>>>(h2, fc2_w, fc2_b, x2, (float*)d_out);
}